// Round 5
// baseline (864.995 us; speedup 1.0000x reference)
//
#include <hip/hip_runtime.h>
#include <math.h>

#define Bq   4
#define Sq   2048
#define CIN  512
#define NH   8
#define CH   64
#define HC   512   // NH*CH

typedef __attribute__((ext_vector_type(8))) short bf16x8;
typedef __attribute__((ext_vector_type(4))) float f32x4;

__device__ __forceinline__ f32x4 MFMA(bf16x8 a, bf16x8 b, f32x4 c) {
    return __builtin_amdgcn_mfma_f32_16x16x32_bf16(a, b, c, 0, 0, 0);
}

// Exact split: f = hi + lo + O(2^-15 |f|). hi is truncated bf16 (exact prefix),
// lo = bf16(f - hi) where f - hi is exactly representable in fp32.
__device__ __forceinline__ void splitf(float f, unsigned short& h, unsigned short& l) {
    unsigned int u = __float_as_uint(f);
    h = (unsigned short)(u >> 16);
    float fh = __uint_as_float(u & 0xFFFF0000u);
    l = (unsigned short)(__float_as_uint(f - fh) >> 16);
}

__device__ __forceinline__ void cvt4(float4 v, ushort4& h, ushort4& l) {
    splitf(v.x, h.x, l.x); splitf(v.y, h.y, l.y);
    splitf(v.z, h.z, l.z); splitf(v.w, h.w, l.w);
}

union FRAG8 { ushort4 u4[2]; bf16x8 v; };

// ---------------------------------------------------------------------------
// Generic C = A @ W^T in bf16x3 split precision.
// A: M x K row-major fp32.  W: N x K row-major fp32 (i.e. B^T form).
// Tile 128x128, BK=64, 256 threads = 4 waves (2x2), each wave 64x64 (4x4 MFMA).
// MODE 0: C = acc*scale  -> (B,NH,S,CH) layout      (Q / K projection)
// MODE 1: C = acc        -> (B,NH,CH,S) layout      (V^T projection)
// MODE 2: C = acc + bias -> plain [M][N]            (output projection)
// MODE 3: C = sigmoid(acc+bias) * Oin[M][N]         (gate)
// ---------------------------------------------------------------------------
template<int MODE>
__global__ __launch_bounds__(256) void gemm_bt(
    const float* __restrict__ A, const float* __restrict__ W,
    const float* __restrict__ bias, const float* __restrict__ Oin,
    float* __restrict__ C, int M, int N, int K, float scale)
{
    __shared__ unsigned short Ah[128][72], Al[128][72];
    __shared__ unsigned short Bh[128][72], Bl[128][72];

    const int t    = threadIdx.x;
    const int lane = t & 63;
    const int w    = t >> 6;
    const int l16  = lane & 15;
    const int g    = lane >> 4;          // 0..3
    const int m0   = blockIdx.x * 128;
    const int n0   = blockIdx.y * 128;
    const int wm   = (w >> 1) * 64;
    const int wn   = (w & 1) * 64;
    const int srow = t >> 4;             // 0..15
    const int scol = (t & 15) * 4;       // 0..60

    const f32x4 z4 = {0.f, 0.f, 0.f, 0.f};
    f32x4 acc[4][4];
#pragma unroll
    for (int m = 0; m < 4; ++m)
#pragma unroll
        for (int n = 0; n < 4; ++n) acc[m][n] = z4;

    for (int kt = 0; kt < K; kt += 64) {
        __syncthreads();
#pragma unroll
        for (int s = 0; s < 8; ++s) {
            const int r = srow + s * 16;
            float4 av = *(const float4*)&A[(size_t)(m0 + r) * K + kt + scol];
            ushort4 h, l; cvt4(av, h, l);
            *(ushort4*)&Ah[r][scol] = h; *(ushort4*)&Al[r][scol] = l;
            float4 bv = *(const float4*)&W[(size_t)(n0 + r) * K + kt + scol];
            cvt4(bv, h, l);
            *(ushort4*)&Bh[r][scol] = h; *(ushort4*)&Bl[r][scol] = l;
        }
        __syncthreads();
#pragma unroll
        for (int kk = 0; kk < 2; ++kk) {
            const int ko = kk * 32 + g * 8;
            bf16x8 bh[4], bl[4];
#pragma unroll
            for (int n = 0; n < 4; ++n) {
                bh[n] = *(const bf16x8*)&Bh[wn + n * 16 + l16][ko];
                bl[n] = *(const bf16x8*)&Bl[wn + n * 16 + l16][ko];
            }
#pragma unroll
            for (int m = 0; m < 4; ++m) {
                bf16x8 ah = *(const bf16x8*)&Ah[wm + m * 16 + l16][ko];
                bf16x8 al = *(const bf16x8*)&Al[wm + m * 16 + l16][ko];
#pragma unroll
                for (int n = 0; n < 4; ++n) {
                    acc[m][n] = MFMA(ah, bh[n], acc[m][n]);
                    acc[m][n] = MFMA(ah, bl[n], acc[m][n]);
                    acc[m][n] = MFMA(al, bh[n], acc[m][n]);
                }
            }
        }
    }

    // epilogue: D layout col = lane&15, row = (lane>>4)*4 + reg  [m89-verified]
#pragma unroll
    for (int m = 0; m < 4; ++m) {
#pragma unroll
        for (int n = 0; n < 4; ++n) {
            const int col = n0 + wn + n * 16 + l16;
#pragma unroll
            for (int r = 0; r < 4; ++r) {
                const int row = m0 + wm + m * 16 + g * 4 + r;
                float v = acc[m][n][r];
                if (MODE == 0) {
                    const int b = row >> 11, s = row & 2047;
                    const int h = col >> 6,  d = col & 63;
                    C[(((size_t)b * NH + h) * Sq + s) * CH + d] = v * scale;
                } else if (MODE == 1) {
                    const int b = row >> 11, s = row & 2047;
                    const int h = col >> 6,  d = col & 63;
                    C[(((size_t)b * NH + h) * CH + d) * Sq + s] = v;
                } else if (MODE == 2) {
                    C[(size_t)row * N + col] = v + bias[col];
                } else {
                    float o  = Oin[(size_t)row * N + col];
                    float gt = 1.f / (1.f + __expf(-(v + bias[col])));
                    C[(size_t)row * N + col] = gt * o;
                }
            }
        }
    }
}

// ---------------------------------------------------------------------------
// Flash attention, bf16x3 MFMA. Grid (S/128, NH, B), 256 thr = 4 waves.
// Each wave owns 32 q-rows (m=2 frags) x 64 keys/d (n=4 frags).
// K tile LDS [key][d], VT tile LDS [d][key] (from global V^T), P per-wave rows.
// LDS total = 4*9216 + 2*18432 + 256 = 73.2 KB -> 2 blocks/CU.
// Bank audit: fragment reads row-stride 144B -> 2-way per 16-lane phase (free,
// m136); staging ushort4 writes 1 bank/lane-phase (conflict-free).
// ---------------------------------------------------------------------------
__global__ __launch_bounds__(256) void attn_mfma(
    const float* __restrict__ Q, const float* __restrict__ K,
    const float* __restrict__ VT, const float* __restrict__ bias,
    const int* __restrict__ mask, float* __restrict__ Aout)
{
    __shared__ unsigned short Kh[64][72], Kl[64][72];
    __shared__ unsigned short Vh[64][72], Vl[64][72];
    __shared__ unsigned short Ph[128][72], Pl[128][72];
    __shared__ float moff[64];

    const int t    = threadIdx.x;
    const int lane = t & 63;
    const int w    = t >> 6;
    const int l16  = lane & 15;
    const int g    = lane >> 4;
    const int q0   = blockIdx.x * 128;
    const int h    = blockIdx.y;
    const int b    = blockIdx.z;
    const int wq   = w * 32;

    const float* Qbase = Q  + (((size_t)b * NH + h) * Sq + q0 + wq) * CH;
    const float* Kbase = K  + ((size_t)b * NH + h) * Sq * CH;
    const float* Vbase = VT + ((size_t)b * NH + h) * CH * Sq;
    const float* bbase = bias + (size_t)h * Sq * Sq;

    // Q fragments in registers (read-once)
    bf16x8 qh[2][2], ql[2][2];
#pragma unroll
    for (int m = 0; m < 2; ++m)
#pragma unroll
        for (int kk = 0; kk < 2; ++kk) {
            const int row = m * 16 + l16;
            const int ko  = kk * 32 + g * 8;
            const float* p = Qbase + (size_t)row * CH + ko;
            float4 v0 = *(const float4*)p;
            float4 v1 = *(const float4*)(p + 4);
            FRAG8 fh, fl;
            cvt4(v0, fh.u4[0], fl.u4[0]);
            cvt4(v1, fh.u4[1], fl.u4[1]);
            qh[m][kk] = fh.v; ql[m][kk] = fl.v;
        }

    const f32x4 z4 = {0.f, 0.f, 0.f, 0.f};
    float m_run[2][4], l_run[2][4];
    f32x4 oacc[2][4];
#pragma unroll
    for (int m = 0; m < 2; ++m) {
#pragma unroll
        for (int r = 0; r < 4; ++r) { m_run[m][r] = -1e30f; l_run[m][r] = 0.f; }
#pragma unroll
        for (int n = 0; n < 4; ++n) oacc[m][n] = z4;
    }

    for (int kt = 0; kt < Sq; kt += 64) {
        __syncthreads();   // previous tile's K/VT reads complete
#pragma unroll
        for (int s = 0; s < 4; ++s) {
            const int rr = (t >> 4) + s * 16;      // key-row for K, d-row for VT
            const int cc = (t & 15) * 4;
            float4 kv = *(const float4*)&Kbase[(size_t)(kt + rr) * CH + cc];
            ushort4 hh, ll; cvt4(kv, hh, ll);
            *(ushort4*)&Kh[rr][cc] = hh; *(ushort4*)&Kl[rr][cc] = ll;
            float4 vv = *(const float4*)&Vbase[(size_t)rr * Sq + kt + cc];
            cvt4(vv, hh, ll);
            *(ushort4*)&Vh[rr][cc] = hh; *(ushort4*)&Vl[rr][cc] = ll;
        }
        if (t < 64) moff[t] = (mask[b * Sq + kt + t] == 0) ? -1e8f : 0.f;
        __syncthreads();

        // ---- S = Q K^T ----
        f32x4 sfr[2][4];
#pragma unroll
        for (int m = 0; m < 2; ++m)
#pragma unroll
            for (int n = 0; n < 4; ++n) sfr[m][n] = z4;
#pragma unroll
        for (int kk = 0; kk < 2; ++kk) {
            const int ko = kk * 32 + g * 8;
            bf16x8 kh[4], kl[4];
#pragma unroll
            for (int n = 0; n < 4; ++n) {
                kh[n] = *(const bf16x8*)&Kh[n * 16 + l16][ko];
                kl[n] = *(const bf16x8*)&Kl[n * 16 + l16][ko];
            }
#pragma unroll
            for (int m = 0; m < 2; ++m)
#pragma unroll
                for (int n = 0; n < 4; ++n) {
                    sfr[m][n] = MFMA(qh[m][kk], kh[n], sfr[m][n]);
                    sfr[m][n] = MFMA(qh[m][kk], kl[n], sfr[m][n]);
                    sfr[m][n] = MFMA(ql[m][kk], kh[n], sfr[m][n]);
                }
        }

        // ---- bias + mask ----
#pragma unroll
        for (int m = 0; m < 2; ++m)
#pragma unroll
            for (int n = 0; n < 4; ++n) {
                const int colk = n * 16 + l16;
                const float mo = moff[colk];
#pragma unroll
                for (int r = 0; r < 4; ++r) {
                    const int qrow = q0 + wq + m * 16 + g * 4 + r;
                    sfr[m][n][r] += bbase[(size_t)qrow * Sq + kt + colk] + mo;
                }
            }

        // ---- online softmax (rows live across the 16 lanes of an l16 group) ----
#pragma unroll
        for (int m = 0; m < 2; ++m) {
#pragma unroll
            for (int r = 0; r < 4; ++r) {
                float mx = fmaxf(fmaxf(sfr[m][0][r], sfr[m][1][r]),
                                 fmaxf(sfr[m][2][r], sfr[m][3][r]));
                mx = fmaxf(mx, __shfl_xor(mx, 1));
                mx = fmaxf(mx, __shfl_xor(mx, 2));
                mx = fmaxf(mx, __shfl_xor(mx, 4));
                mx = fmaxf(mx, __shfl_xor(mx, 8));
                const float newm = fmaxf(m_run[m][r], mx);
                const float corr = __expf(m_run[m][r] - newm);
                m_run[m][r] = newm;
                float rs = 0.f;
#pragma unroll
                for (int n = 0; n < 4; ++n) {
                    float p = __expf(sfr[m][n][r] - newm);
                    sfr[m][n][r] = p;
                    rs += p;
                }
                rs += __shfl_xor(rs, 1);
                rs += __shfl_xor(rs, 2);
                rs += __shfl_xor(rs, 4);
                rs += __shfl_xor(rs, 8);
                l_run[m][r] = l_run[m][r] * corr + rs;
#pragma unroll
                for (int n = 0; n < 4; ++n) oacc[m][n][r] *= corr;
                // write P (hi/lo) to this wave's private P rows
                const int prow = wq + m * 16 + g * 4 + r;
#pragma unroll
                for (int n = 0; n < 4; ++n) {
                    unsigned short hh, ll;
                    splitf(sfr[m][n][r], hh, ll);
                    Ph[prow][n * 16 + l16] = hh;
                    Pl[prow][n * 16 + l16] = ll;
                }
            }
        }

        // ---- O += P V  (wave-local P rows; in-wave DS ordering, no barrier) ----
#pragma unroll
        for (int kk = 0; kk < 2; ++kk) {
            const int ko = kk * 32 + g * 8;
            bf16x8 vh[4], vl[4];
#pragma unroll
            for (int n = 0; n < 4; ++n) {
                vh[n] = *(const bf16x8*)&Vh[n * 16 + l16][ko];
                vl[n] = *(const bf16x8*)&Vl[n * 16 + l16][ko];
            }
#pragma unroll
            for (int m = 0; m < 2; ++m) {
                bf16x8 ph = *(const bf16x8*)&Ph[wq + m * 16 + l16][ko];
                bf16x8 pl = *(const bf16x8*)&Pl[wq + m * 16 + l16][ko];
#pragma unroll
                for (int n = 0; n < 4; ++n) {
                    oacc[m][n] = MFMA(ph, vh[n], oacc[m][n]);
                    oacc[m][n] = MFMA(ph, vl[n], oacc[m][n]);
                    oacc[m][n] = MFMA(pl, vh[n], oacc[m][n]);
                }
            }
        }
    }

    // ---- epilogue: normalize and store (B,S,H*C) ----
#pragma unroll
    for (int m = 0; m < 2; ++m)
#pragma unroll
        for (int r = 0; r < 4; ++r) {
            const float inv = 1.f / l_run[m][r];
            const int row = q0 + wq + m * 16 + g * 4 + r;
#pragma unroll
            for (int n = 0; n < 4; ++n)
                Aout[((size_t)b * Sq + row) * HC + h * CH + n * 16 + l16] =
                    oacc[m][n][r] * inv;
        }
}

// ---------------------------------------------------------------------------
extern "C" void kernel_launch(void* const* d_in, const int* in_sizes, int n_in,
                              void* d_out, int out_size, void* d_ws, size_t ws_size,
                              hipStream_t stream)
{
    const float* x    = (const float*)d_in[0];
    const float* bias = (const float*)d_in[1];
    const int*   mask = (const int*)d_in[2];
    const float* Wq   = (const float*)d_in[3];
    const float* Wk   = (const float*)d_in[4];
    const float* Wv   = (const float*)d_in[5];
    const float* Wo   = (const float*)d_in[6];
    const float* bo   = (const float*)d_in[7];
    const float* Wg   = (const float*)d_in[8];
    const float* bg   = (const float*)d_in[9];
    float* out = (float*)d_out;
    float* ws  = (float*)d_ws;

    const size_t QS = (size_t)Bq * NH * Sq * CH;   // 4,194,304 elements
    float* Q    = ws;            // (B,H,S,C)   } Q region reused for O after attn
    float* Kt   = ws + QS;       // (B,H,S,C)
    float* VT   = ws + 2 * QS;   // (B,H,C,S)
    float* attn = ws + 3 * QS;   // (B,S,H*C)
    float* O    = Q;             // overlay: Q dead after attn  (peak ws = 64 MB)

    const int M = Bq * Sq;       // 8192
    dim3 gg(M / 128, HC / 128);  // (64, 4)

    gemm_bt<0><<<gg, 256, 0, stream>>>(x, Wq, nullptr, nullptr, Q,  M, HC, CIN, 0.125f);
    gemm_bt<0><<<gg, 256, 0, stream>>>(x, Wk, nullptr, nullptr, Kt, M, HC, CIN, 1.0f);
    gemm_bt<1><<<gg, 256, 0, stream>>>(x, Wv, nullptr, nullptr, VT, M, HC, CIN, 1.0f);

    attn_mfma<<<dim3(Sq / 128, NH, Bq), 256, 0, stream>>>(Q, Kt, VT, bias, mask, attn);

    gemm_bt<2><<<gg, 256, 0, stream>>>(attn, Wo, bo, nullptr, O,   M, HC, HC, 1.0f);
    gemm_bt<3><<<gg, 256, 0, stream>>>(O,    Wg, bg, O,       out, M, HC, HC, 1.0f);
}

// Round 8
// 486.607 us; speedup vs baseline: 1.7776x; 1.7776x over previous
//
#include <hip/hip_runtime.h>
#include <math.h>

#define Bq   4
#define Sq   2048
#define CIN  512
#define NH   8
#define CH   64
#define HC   512   // NH*CH

typedef __attribute__((ext_vector_type(8))) short bf16x8;
typedef __attribute__((ext_vector_type(4))) float f32x4;

__device__ __forceinline__ f32x4 MFMA(bf16x8 a, bf16x8 b, f32x4 c) {
    return __builtin_amdgcn_mfma_f32_16x16x32_bf16(a, b, c, 0, 0, 0);
}

// Exact split: f = hi + lo + O(2^-15 |f|).
__device__ __forceinline__ void splitf(float f, unsigned short& h, unsigned short& l) {
    unsigned int u = __float_as_uint(f);
    h = (unsigned short)(u >> 16);
    float fh = __uint_as_float(u & 0xFFFF0000u);
    l = (unsigned short)(__float_as_uint(f - fh) >> 16);
}

__device__ __forceinline__ void cvt4(float4 v, ushort4& h, ushort4& l) {
    splitf(v.x, h.x, l.x); splitf(v.y, h.y, l.y);
    splitf(v.z, h.z, l.z); splitf(v.w, h.w, l.w);
}

union FRAG8 { ushort4 u4[2]; bf16x8 v; };

// ---------------------------------------------------------------------------
// Fused QKV projection, bf16x3. Tile 128(M)x64(N), BK=64, 4 waves (2x2),
// each wave 64x32 (4m x 2n frags). Grid (64, 24): y>>3 selects Q/K/V,
// (y&7)*64 is the column tile inside the 512-wide W.
// LDS 55.3 KB -> 2 blocks/CU (round-5 GEMMs were 1 block/CU latency-bound).
// ---------------------------------------------------------------------------
__global__ __launch_bounds__(256) void qkv_fused(
    const float* __restrict__ x,
    const float* __restrict__ Wq, const float* __restrict__ Wk,
    const float* __restrict__ Wv,
    float* __restrict__ Qo, float* __restrict__ Ko, float* __restrict__ Vo)
{
    __shared__ unsigned short Ah[128][72], Al[128][72];
    __shared__ unsigned short Bh[64][72],  Bl[64][72];

    const int t    = threadIdx.x;
    const int lane = t & 63;
    const int w    = t >> 6;
    const int l16  = lane & 15;
    const int g    = lane >> 4;
    const int m0   = blockIdx.x * 128;
    const int by   = blockIdx.y;
    const int sel  = by >> 3;            // 0=Q 1=K 2=V
    const int n0   = (by & 7) * 64;      // column tile in W
    const float* __restrict__ W = (sel == 0) ? Wq : (sel == 1) ? Wk : Wv;
    const int wm   = (w >> 1) * 64;
    const int wn   = (w & 1) * 32;
    const int srow = t >> 4;
    const int scol = (t & 15) * 4;

    const f32x4 z4 = {0.f, 0.f, 0.f, 0.f};
    f32x4 acc[4][2];
#pragma unroll
    for (int m = 0; m < 4; ++m)
#pragma unroll
        for (int n = 0; n < 2; ++n) acc[m][n] = z4;

    for (int kt = 0; kt < CIN; kt += 64) {
        __syncthreads();
#pragma unroll
        for (int s = 0; s < 8; ++s) {
            const int r = srow + s * 16;
            float4 av = *(const float4*)&x[(size_t)(m0 + r) * CIN + kt + scol];
            ushort4 h, l; cvt4(av, h, l);
            *(ushort4*)&Ah[r][scol] = h; *(ushort4*)&Al[r][scol] = l;
        }
#pragma unroll
        for (int s = 0; s < 4; ++s) {
            const int r = srow + s * 16;
            float4 bv = *(const float4*)&W[(size_t)(n0 + r) * CIN + kt + scol];
            ushort4 h, l; cvt4(bv, h, l);
            *(ushort4*)&Bh[r][scol] = h; *(ushort4*)&Bl[r][scol] = l;
        }
        __syncthreads();
#pragma unroll
        for (int kk = 0; kk < 2; ++kk) {
            const int ko = kk * 32 + g * 8;
            bf16x8 bh[2], bl[2];
#pragma unroll
            for (int n = 0; n < 2; ++n) {
                bh[n] = *(const bf16x8*)&Bh[wn + n * 16 + l16][ko];
                bl[n] = *(const bf16x8*)&Bl[wn + n * 16 + l16][ko];
            }
#pragma unroll
            for (int m = 0; m < 4; ++m) {
                bf16x8 ah = *(const bf16x8*)&Ah[wm + m * 16 + l16][ko];
                bf16x8 al = *(const bf16x8*)&Al[wm + m * 16 + l16][ko];
#pragma unroll
                for (int n = 0; n < 2; ++n) {
                    acc[m][n] = MFMA(ah, bh[n], acc[m][n]);
                    acc[m][n] = MFMA(ah, bl[n], acc[m][n]);
                    acc[m][n] = MFMA(al, bh[n], acc[m][n]);
                }
            }
        }
    }

#pragma unroll
    for (int m = 0; m < 4; ++m)
#pragma unroll
        for (int n = 0; n < 2; ++n) {
            const int col = n0 + wn + n * 16 + l16;   // 0..511
            const int hh  = col >> 6, d = col & 63;
#pragma unroll
            for (int r = 0; r < 4; ++r) {
                const int row = m0 + wm + m * 16 + g * 4 + r;
                const int b = row >> 11, s = row & 2047;
                float v = acc[m][n][r];
                if (sel == 0)
                    Qo[(((size_t)b * NH + hh) * Sq + s) * CH + d] = v * 0.125f;
                else if (sel == 1)
                    Ko[(((size_t)b * NH + hh) * Sq + s) * CH + d] = v;
                else
                    Vo[(((size_t)b * NH + hh) * CH + d) * Sq + s] = v;
            }
        }
}

// ---------------------------------------------------------------------------
// Out-proj / gate GEMM, bf16x3, tile 128x64, grid (64, 8) = 512 blocks = 2/CU.
// MODE 2: C = acc + bias.   MODE 3: C = sigmoid(acc+bias) * Oin.
// ---------------------------------------------------------------------------
template<int MODE>
__global__ __launch_bounds__(256) void gemm_og(
    const float* __restrict__ A, const float* __restrict__ W,
    const float* __restrict__ bias, const float* __restrict__ Oin,
    float* __restrict__ C)
{
    __shared__ unsigned short Ah[128][72], Al[128][72];
    __shared__ unsigned short Bh[64][72],  Bl[64][72];

    const int t    = threadIdx.x;
    const int lane = t & 63;
    const int w    = t >> 6;
    const int l16  = lane & 15;
    const int g    = lane >> 4;
    const int m0   = blockIdx.x * 128;
    const int n0   = blockIdx.y * 64;
    const int wm   = (w >> 1) * 64;
    const int wn   = (w & 1) * 32;
    const int srow = t >> 4;
    const int scol = (t & 15) * 4;

    const f32x4 z4 = {0.f, 0.f, 0.f, 0.f};
    f32x4 acc[4][2];
#pragma unroll
    for (int m = 0; m < 4; ++m)
#pragma unroll
        for (int n = 0; n < 2; ++n) acc[m][n] = z4;

    for (int kt = 0; kt < HC; kt += 64) {
        __syncthreads();
#pragma unroll
        for (int s = 0; s < 8; ++s) {
            const int r = srow + s * 16;
            float4 av = *(const float4*)&A[(size_t)(m0 + r) * HC + kt + scol];
            ushort4 h, l; cvt4(av, h, l);
            *(ushort4*)&Ah[r][scol] = h; *(ushort4*)&Al[r][scol] = l;
        }
#pragma unroll
        for (int s = 0; s < 4; ++s) {
            const int r = srow + s * 16;
            float4 bv = *(const float4*)&W[(size_t)(n0 + r) * HC + kt + scol];
            ushort4 h, l; cvt4(bv, h, l);
            *(ushort4*)&Bh[r][scol] = h; *(ushort4*)&Bl[r][scol] = l;
        }
        __syncthreads();
#pragma unroll
        for (int kk = 0; kk < 2; ++kk) {
            const int ko = kk * 32 + g * 8;
            bf16x8 bh[2], bl[2];
#pragma unroll
            for (int n = 0; n < 2; ++n) {
                bh[n] = *(const bf16x8*)&Bh[wn + n * 16 + l16][ko];
                bl[n] = *(const bf16x8*)&Bl[wn + n * 16 + l16][ko];
            }
#pragma unroll
            for (int m = 0; m < 4; ++m) {
                bf16x8 ah = *(const bf16x8*)&Ah[wm + m * 16 + l16][ko];
                bf16x8 al = *(const bf16x8*)&Al[wm + m * 16 + l16][ko];
#pragma unroll
                for (int n = 0; n < 2; ++n) {
                    acc[m][n] = MFMA(ah, bh[n], acc[m][n]);
                    acc[m][n] = MFMA(ah, bl[n], acc[m][n]);
                    acc[m][n] = MFMA(al, bh[n], acc[m][n]);
                }
            }
        }
    }

#pragma unroll
    for (int m = 0; m < 4; ++m)
#pragma unroll
        for (int n = 0; n < 2; ++n) {
            const int col = n0 + wn + n * 16 + l16;
#pragma unroll
            for (int r = 0; r < 4; ++r) {
                const int row = m0 + wm + m * 16 + g * 4 + r;
                float v = acc[m][n][r];
                if (MODE == 2) {
                    C[(size_t)row * HC + col] = v + bias[col];
                } else {
                    float o  = Oin[(size_t)row * HC + col];
                    float gt = 1.f / (1.f + __expf(-(v + bias[col])));
                    C[(size_t)row * HC + col] = gt * o;
                }
            }
        }
}

// ---------------------------------------------------------------------------
// Flash attention, bf16x3 MFMA. Grid (S/128, NH, B), 256 thr = 4 waves.
// Bias goes through wave-private LDS (coalesced float4 stage after the first
// barrier, consumed after QK), replacing the 32 scalar global loads per lane
// per tile that made round-5 latency-bound (MfmaUtil 9%, VALU 19%, HBM 6%).
// The bias tile aliases the wave-private P tile. Alias safety:
//  - stage is AFTER __syncthreads() (full compiler+HW fence) -> strictly
//    after the previous tile's PV reads of this region;
//  - a compiler-only memory fence separates bias reads (float) from P writes
//    (ushort) in the same tile, closing the TBAA reordering hole.
// LDS = 36864 (K/V) + 36864 (Pbuf) + 256 = 74 KB -> 2 blocks/CU.
// ---------------------------------------------------------------------------
__global__ __launch_bounds__(256) void attn_mfma(
    const float* __restrict__ Q, const float* __restrict__ K,
    const float* __restrict__ VT, const float* __restrict__ bias,
    const int* __restrict__ mask, float* __restrict__ Aout)
{
    __shared__ unsigned short Kh[64][72], Kl[64][72];
    __shared__ unsigned short Vh[64][72], Vl[64][72];
    __shared__ __align__(16) unsigned char Pbuf[4][9216];  // per-wave chunk
    __shared__ float moff[64];

    const int t    = threadIdx.x;
    const int lane = t & 63;
    const int w    = t >> 6;
    const int l16  = lane & 15;
    const int g    = lane >> 4;
    const int q0   = blockIdx.x * 128;
    const int h    = blockIdx.y;
    const int b    = blockIdx.z;
    const int wq   = w * 32;

    // per-wave chunk: Ph[32][72] ushort | Pl[32][72] ushort, aliased by
    // Bs[32][68] float (bias tile). All rows wave-private.
    unsigned short* Phw = (unsigned short*)(Pbuf[w]);
    unsigned short* Plw = Phw + 32 * 72;
    float*          Bsw = (float*)(Pbuf[w]);

    const float* Qbase = Q  + (((size_t)b * NH + h) * Sq + q0 + wq) * CH;
    const float* Kbase = K  + ((size_t)b * NH + h) * Sq * CH;
    const float* Vbase = VT + ((size_t)b * NH + h) * CH * Sq;
    const float* bbase = bias + (size_t)h * Sq * Sq;

    // Q fragments in registers
    bf16x8 qh[2][2], ql[2][2];
#pragma unroll
    for (int m = 0; m < 2; ++m)
#pragma unroll
        for (int kk = 0; kk < 2; ++kk) {
            const int row = m * 16 + l16;
            const int ko  = kk * 32 + g * 8;
            const float* p = Qbase + (size_t)row * CH + ko;
            float4 v0 = *(const float4*)p;
            float4 v1 = *(const float4*)(p + 4);
            FRAG8 fh, fl;
            cvt4(v0, fh.u4[0], fl.u4[0]);
            cvt4(v1, fh.u4[1], fl.u4[1]);
            qh[m][kk] = fh.v; ql[m][kk] = fl.v;
        }

    const f32x4 z4 = {0.f, 0.f, 0.f, 0.f};
    float m_run[2][4], l_run[2][4];
    f32x4 oacc[2][4];
#pragma unroll
    for (int m = 0; m < 2; ++m) {
#pragma unroll
        for (int r = 0; r < 4; ++r) { m_run[m][r] = -1e30f; l_run[m][r] = 0.f; }
#pragma unroll
        for (int n = 0; n < 4; ++n) oacc[m][n] = z4;
    }

    const int brow = lane >> 4;          // bias stage: 0..3
    const int bcol = (lane & 15) * 4;    // 0..60

    for (int kt = 0; kt < Sq; kt += 64) {
        __syncthreads();   // prev tile's K/VT reads AND PV P-reads complete

        // stage this tile's bias rows (wave-private; overlaps K/V staging
        // below and the QK MFMAs after the barrier)
#pragma unroll
        for (int s = 0; s < 8; ++s) {
            const int rl = brow + s * 4;   // 0..31
            *(float4*)&Bsw[rl * 68 + bcol] =
                *(const float4*)&bbase[(size_t)(q0 + wq + rl) * Sq + kt + bcol];
        }

#pragma unroll
        for (int s = 0; s < 4; ++s) {
            const int rr = (t >> 4) + s * 16;
            const int cc = (t & 15) * 4;
            float4 kv = *(const float4*)&Kbase[(size_t)(kt + rr) * CH + cc];
            ushort4 hh, ll; cvt4(kv, hh, ll);
            *(ushort4*)&Kh[rr][cc] = hh; *(ushort4*)&Kl[rr][cc] = ll;
            float4 vv = *(const float4*)&Vbase[(size_t)rr * Sq + kt + cc];
            cvt4(vv, hh, ll);
            *(ushort4*)&Vh[rr][cc] = hh; *(ushort4*)&Vl[rr][cc] = ll;
        }
        if (t < 64) moff[t] = (mask[b * Sq + kt + t] == 0) ? -1e8f : 0.f;
        __syncthreads();

        // ---- S = Q K^T ----
        f32x4 sfr[2][4];
#pragma unroll
        for (int m = 0; m < 2; ++m)
#pragma unroll
            for (int n = 0; n < 4; ++n) sfr[m][n] = z4;
#pragma unroll
        for (int kk = 0; kk < 2; ++kk) {
            const int ko = kk * 32 + g * 8;
            bf16x8 kh[4], kl[4];
#pragma unroll
            for (int n = 0; n < 4; ++n) {
                kh[n] = *(const bf16x8*)&Kh[n * 16 + l16][ko];
                kl[n] = *(const bf16x8*)&Kl[n * 16 + l16][ko];
            }
#pragma unroll
            for (int m = 0; m < 2; ++m)
#pragma unroll
                for (int n = 0; n < 4; ++n) {
                    sfr[m][n] = MFMA(qh[m][kk], kh[n], sfr[m][n]);
                    sfr[m][n] = MFMA(qh[m][kk], kl[n], sfr[m][n]);
                    sfr[m][n] = MFMA(ql[m][kk], kh[n], sfr[m][n]);
                }
        }

        // ---- bias (from LDS) + mask ----
#pragma unroll
        for (int m = 0; m < 2; ++m)
#pragma unroll
            for (int n = 0; n < 4; ++n) {
                const int colk = n * 16 + l16;
                const float mo = moff[colk];
#pragma unroll
                for (int r = 0; r < 4; ++r)
                    sfr[m][n][r] += Bsw[(m * 16 + g * 4 + r) * 68 + colk] + mo;
            }

        // compiler fence: bias reads (float) must not be reordered with the
        // P-tile writes (ushort) below — they alias (TBAA can't see it).
        asm volatile("" ::: "memory");

        // ---- online softmax ----
#pragma unroll
        for (int m = 0; m < 2; ++m) {
#pragma unroll
            for (int r = 0; r < 4; ++r) {
                float mx = fmaxf(fmaxf(sfr[m][0][r], sfr[m][1][r]),
                                 fmaxf(sfr[m][2][r], sfr[m][3][r]));
                mx = fmaxf(mx, __shfl_xor(mx, 1));
                mx = fmaxf(mx, __shfl_xor(mx, 2));
                mx = fmaxf(mx, __shfl_xor(mx, 4));
                mx = fmaxf(mx, __shfl_xor(mx, 8));
                const float newm = fmaxf(m_run[m][r], mx);
                const float corr = __expf(m_run[m][r] - newm);
                m_run[m][r] = newm;
                float rs = 0.f;
#pragma unroll
                for (int n = 0; n < 4; ++n) {
                    float p = __expf(sfr[m][n][r] - newm);
                    sfr[m][n][r] = p;
                    rs += p;
                }
                rs += __shfl_xor(rs, 1);
                rs += __shfl_xor(rs, 2);
                rs += __shfl_xor(rs, 4);
                rs += __shfl_xor(rs, 8);
                l_run[m][r] = l_run[m][r] * corr + rs;
#pragma unroll
                for (int n = 0; n < 4; ++n) oacc[m][n][r] *= corr;
                const int prl = m * 16 + g * 4 + r;   // wave-local P row
#pragma unroll
                for (int n = 0; n < 4; ++n) {
                    unsigned short hh, ll;
                    splitf(sfr[m][n][r], hh, ll);
                    Phw[prl * 72 + n * 16 + l16] = hh;
                    Plw[prl * 72 + n * 16 + l16] = ll;
                }
            }
        }

        // ---- O += P V  (wave-private P; in-wave DS ordering) ----
#pragma unroll
        for (int kk = 0; kk < 2; ++kk) {
            const int ko = kk * 32 + g * 8;
            bf16x8 vh[4], vl[4];
#pragma unroll
            for (int n = 0; n < 4; ++n) {
                vh[n] = *(const bf16x8*)&Vh[n * 16 + l16][ko];
                vl[n] = *(const bf16x8*)&Vl[n * 16 + l16][ko];
            }
#pragma unroll
            for (int m = 0; m < 2; ++m) {
                bf16x8 ph = *(const bf16x8*)&Phw[(m * 16 + l16) * 72 + ko];
                bf16x8 pl = *(const bf16x8*)&Plw[(m * 16 + l16) * 72 + ko];
#pragma unroll
                for (int n = 0; n < 4; ++n) {
                    oacc[m][n] = MFMA(ph, vh[n], oacc[m][n]);
                    oacc[m][n] = MFMA(ph, vl[n], oacc[m][n]);
                    oacc[m][n] = MFMA(pl, vh[n], oacc[m][n]);
                }
            }
        }
    }

    // ---- epilogue ----
#pragma unroll
    for (int m = 0; m < 2; ++m)
#pragma unroll
        for (int r = 0; r < 4; ++r) {
            const float inv = 1.f / l_run[m][r];
            const int row = q0 + wq + m * 16 + g * 4 + r;
#pragma unroll
            for (int n = 0; n < 4; ++n)
                Aout[((size_t)b * Sq + row) * HC + h * CH + n * 16 + l16] =
                    oacc[m][n][r] * inv;
        }
}

// ---------------------------------------------------------------------------
extern "C" void kernel_launch(void* const* d_in, const int* in_sizes, int n_in,
                              void* d_out, int out_size, void* d_ws, size_t ws_size,
                              hipStream_t stream)
{
    const float* x    = (const float*)d_in[0];
    const float* bias = (const float*)d_in[1];
    const int*   mask = (const int*)d_in[2];
    const float* Wq   = (const float*)d_in[3];
    const float* Wk   = (const float*)d_in[4];
    const float* Wv   = (const float*)d_in[5];
    const float* Wo   = (const float*)d_in[6];
    const float* bo   = (const float*)d_in[7];
    const float* Wg   = (const float*)d_in[8];
    const float* bg   = (const float*)d_in[9];
    float* out = (float*)d_out;
    float* ws  = (float*)d_ws;

    const size_t QS = (size_t)Bq * NH * Sq * CH;   // 4,194,304 elements
    float* Q    = ws;            // (B,H,S,C); reused for O after attn
    float* Kt   = ws + QS;       // (B,H,S,C)
    float* VT   = ws + 2 * QS;   // (B,H,C,S)
    float* attn = ws + 3 * QS;   // (B,S,H*C)
    float* O    = Q;             // overlay (Q dead after attn)

    qkv_fused<<<dim3(64, 24), 256, 0, stream>>>(x, Wq, Wk, Wv, Q, Kt, VT);

    attn_mfma<<<dim3(Sq / 128, NH, Bq), 256, 0, stream>>>(Q, Kt, VT, bias, mask, attn);

    gemm_og<2><<<dim3(64, 8), 256, 0, stream>>>(attn, Wo, bo, nullptr, O);
    gemm_og<3><<<dim3(64, 8), 256, 0, stream>>>(O,    Wg, bg, O,       out);
}